// Round 11
// baseline (178.484 us; speedup 1.0000x reference)
//
#include <hip/hip_runtime.h>
#include <math.h>

// GEBLNet via Gram-matrix reduction (R11: single kernel, 2 points/block).
//   T[u] = sum_{v,w} w2[u,v,w] * G[v,w],  G[v,w] = tr(We2[v] @ We2[w]).
// Phase 4 computes the 169 unique Gram values and mirrors them into the full
// 25x25 G in LDS (conjugation symmetries); phase 5 contracts RAW w2 against
// G directly -> no setup kernel, no workspace, one dispatch.
// Execution shape: 4096 blocks x 128 threads; each WAVE owns one point and
// runs all phases on its private LDS slice (wave-synchronous, barriers just
// couple two symmetric waves). Doubles waves per workgroup slot vs R10
// (R10: 1-wave blocks capped by the ~16 workgroup/CU limit at ~36% occ).
// Register diet (R10-proven, VGPR=64): phase-2 w-range in two sequential
// halves (#pragma unroll 1), v-loop unroll 1 (stops global-load pipelining
// from hoarding ~50 regs — R9 evidence).
// LESSON (R4+R7): launch_bounds min-waves arg -> 64-VGPR quantize + spill.
// LESSON (R6): never reinterpret-cast local arrays (alloca -> scratch).

#define NPTS 8192
#define THRESH 0.001f

__global__ __launch_bounds__(128) void geblnet_main(
    const float2* __restrict__ x2,      // (8192, 10, 9) complex
    const float2* __restrict__ w1g,     // (12,13,13) complex
    const float2* __restrict__ w2c,     // (12,25,25) complex
    const float* __restrict__ dw,       // (24,)
    const float* __restrict__ db,       // (1,)
    float* __restrict__ out)            // (8192,)
{
    // Per-wave slices. Gs overlays: phases 1-2 = We1 row-major (stride 10,
    // first 120 slots); phases 4-5 = full 25x25 Gram matrix (625 slots).
    __shared__ float2 Gs[2][625];       // 10000 B
    // k-major: Wcol[w][k*44 + ch*3 + j] = We[ch][j][k]; ch=12 identity at
    // 36..38; slots 39..41 ZERO (pad for h=1's 7th unroll slot).
    __shared__ float2 Wcol[2][3 * 44];  //  2112 B
    __shared__ float2 Hs[2][108];       //  1728 B
    __shared__ float2 Tpar[2][60];      //   960 B
    __shared__ float2 tr1[2][12];       //   192 B
    __shared__ float  sc1[2][12];       //    96 B
    __shared__ float  gb[2][12];        //    96 B
    __shared__ float  tra[2][12];       //    96 B

    const int t = threadIdx.x;
    const int wv = t >> 6;              // wave id = point sub-index
    const int l = t & 63;               // lane in wave
    const int p = blockIdx.x * 2 + wv;  // NPTS=8192=2*4096: always valid

    float2* We = Gs[wv];                // row-major We1, stride 10

    // ---- phase 1: build We1 in row-major (v<12) and k-major layouts
    for (int j = l; j < 117; j += 64) {
        int v = j / 9, ik = j - v * 9;
        int i = ik / 3, jj = ik - i * 3;
        if (v < 12) {
            const float2* xp = x2 + (size_t)p * 90;
            float2 val;
            if (v < 6) val = xp[(4 + v) * 9 + ik];
            else { float2 s = xp[(v - 2) * 9 + jj * 3 + i]; val = make_float2(s.x, -s.y); }
            We[v * 10 + ik] = val;                  // row-major
            Wcol[wv][jj * 44 + v * 3 + i] = val;    // k-major (k=jj)
        } else {
            Wcol[wv][jj * 44 + 36 + i] = make_float2((i == jj) ? 1.f : 0.f, 0.f);
            Wcol[wv][jj * 44 + 39 + i] = make_float2(0.f, 0.f);   // zero pad
        }
    }
    __syncthreads();

    // ---- phase 2: layer 1, lane=(u,k), sequential w-halves (R10-proven)
    if (l < 36) {
        int u = l / 3, k = l - u * 3;
        const float2* wrow = w1g + u * 169;
        float h0r = 0.f, h0i = 0.f, h1r = 0.f, h1i = 0.f, h2r = 0.f, h2i = 0.f;

        #pragma unroll 1
        for (int h = 0; h < 2; ++h) {
            const float2* wcb = &Wcol[wv][k * 44 + h * 21];   // ch = 7h + m
            float2 wc[7][3];
            #pragma unroll
            for (int m = 0; m < 7; ++m) {
                wc[m][0] = wcb[m * 3 + 0];
                wc[m][1] = wcb[m * 3 + 1];
                wc[m][2] = wcb[m * 3 + 2];
            }
            const int wlast = h ? 12 : 6;   // clamp for the padded slot

            #pragma unroll 1
            for (int v = 0; v < 13; ++v) {
                const float2* cp = wrow + v * 13 + h * 7;
                float b0r = 0.f, b0i = 0.f, b1r = 0.f, b1i = 0.f, b2r = 0.f, b2i = 0.f;
                #pragma unroll
                for (int m = 0; m < 7; ++m) {
                    float2 cc = (m == 6) ? wrow[v * 13 + wlast] : cp[m];
                    float2 e0 = wc[m][0], e1 = wc[m][1], e2 = wc[m][2];
                    b0r += cc.x * e0.x - cc.y * e0.y;  b0i += cc.x * e0.y + cc.y * e0.x;
                    b1r += cc.x * e1.x - cc.y * e1.y;  b1i += cc.x * e1.y + cc.y * e1.x;
                    b2r += cc.x * e2.x - cc.y * e2.y;  b2i += cc.x * e2.y + cc.y * e2.x;
                }
                if (v < 12) {
                    const float2* a = &We[v * 10];
                    {
                        float2 a0 = a[0], a1 = a[1], a2 = a[2];
                        h0r += a0.x * b0r - a0.y * b0i + a1.x * b1r - a1.y * b1i + a2.x * b2r - a2.y * b2i;
                        h0i += a0.x * b0i + a0.y * b0r + a1.x * b1i + a1.y * b1r + a2.x * b2i + a2.y * b2r;
                    }
                    {
                        float2 a0 = a[3], a1 = a[4], a2 = a[5];
                        h1r += a0.x * b0r - a0.y * b0i + a1.x * b1r - a1.y * b1i + a2.x * b2r - a2.y * b2i;
                        h1i += a0.x * b0i + a0.y * b0r + a1.x * b1i + a1.y * b1r + a2.x * b2i + a2.y * b2r;
                    }
                    {
                        float2 a0 = a[6], a1 = a[7], a2 = a[8];
                        h2r += a0.x * b0r - a0.y * b0i + a1.x * b1r - a1.y * b1i + a2.x * b2r - a2.y * b2i;
                        h2i += a0.x * b0i + a0.y * b0r + a1.x * b1i + a1.y * b1r + a2.x * b2i + a2.y * b2r;
                    }
                } else {                  // We[12] = I  ->  H += B(partial)
                    h0r += b0r; h0i += b0i;
                    h1r += b1r; h1i += b1i;
                    h2r += b2r; h2i += b2i;
                }
            }
        }
        Hs[wv][u * 9 + 0 + k] = make_float2(h0r, h0i);
        Hs[wv][u * 9 + 3 + k] = make_float2(h1r, h1i);
        Hs[wv][u * 9 + 6 + k] = make_float2(h2r, h2i);
    }
    __syncthreads();

    // ---- phase 3: traces + gerelu + trnorm scales
    if (l < 12) {
        float2 a = Hs[wv][l * 9 + 0], b = Hs[wv][l * 9 + 4], c = Hs[wv][l * 9 + 8];
        float2 tt = make_float2(a.x + b.x + c.x, a.y + b.y + c.y);
        tr1[wv][l] = tt;
        float gg = tt.x > 0.f ? tt.x : 0.f;
        gb[wv][l] = gg;
        tra[wv][l] = gg * sqrtf(tt.x * tt.x + tt.y * tt.y);
    }
    __syncthreads();
    if (l < 12) {
        float m = 0.f;
        #pragma unroll
        for (int u = 0; u < 12; ++u) m += tra[wv][u];
        sc1[wv][l] = gb[wv][l] / fmaxf(m * (1.f / 12.f), THRESH);
    }
    __syncthreads();

    // ---- phase 4: 169 unique Gram values, mirrored into full 25x25 G
    // (overlays We row-major region; We dead since phase 2)
    {
        float2* G = Gs[wv];
        for (int it = l; it < 169; it += 64) {
            if (it < 156) {
                int q = it < 78 ? it : it - 78;
                float fs = sqrtf(625.0f - 8.0f * (float)q);   // exact at bucket edges
                int a = (int)((25.0f - fs) * 0.5f);
                int b = q - (a * (25 - a)) / 2 + a;
                const float2* Ha = &Hs[wv][a * 9];
                const float2* Hb = &Hs[wv][b * 9];
                float s = sc1[wv][a] * sc1[wv][b];
                float vr = 0.f, vi = 0.f;
                if (it < 78) {                    // S = tr(Aa Ab)
                    #pragma unroll
                    for (int i = 0; i < 3; ++i)
                        #pragma unroll
                        for (int jj = 0; jj < 3; ++jj) {
                            float2 A = Ha[i * 3 + jj], B = Hb[jj * 3 + i];
                            vr += A.x * B.x - A.y * B.y;
                            vi += A.x * B.y + A.y * B.x;
                        }
                    float2 val = make_float2(s * vr, s * vi);
                    float2 cvl = make_float2(s * vr, -s * vi);
                    G[a * 25 + b] = val;               // G[a,b]
                    G[b * 25 + a] = val;               // G[b,a]
                    G[(12 + a) * 25 + 12 + b] = cvl;   // conj
                    G[(12 + b) * 25 + 12 + a] = cvl;
                } else {                          // Hm = tr(Aa Ab^H)
                    #pragma unroll
                    for (int e = 0; e < 9; ++e) {
                        float2 A = Ha[e], B = Hb[e];
                        vr += A.x * B.x + A.y * B.y;
                        vi += A.y * B.x - A.x * B.y;
                    }
                    float2 val = make_float2(s * vr, s * vi);
                    float2 cvl = make_float2(s * vr, -s * vi);
                    G[a * 25 + 12 + b] = val;          // G[a,12+b]
                    G[(12 + b) * 25 + a] = val;        // G[12+b,a]
                    G[b * 25 + 12 + a] = cvl;          // conj
                    G[(12 + a) * 25 + b] = cvl;
                }
            } else if (it < 168) {
                int a = it - 156;
                float s = sc1[wv][a]; float2 tt = tr1[wv][a];
                float2 val = make_float2(s * tt.x, s * tt.y);
                float2 cvl = make_float2(s * tt.x, -s * tt.y);
                G[a * 25 + 24] = val;  G[24 * 25 + a] = val;
                G[(12 + a) * 25 + 24] = cvl;  G[24 * 25 + 12 + a] = cvl;
            } else {
                G[24 * 25 + 24] = make_float2(3.f, 0.f);   // tr(I)
            }
        }
    }
    __syncthreads();

    // ---- phase 5: direct contraction T[u] = sum_e w2[u][e] * G[e]
    if (l < 60) {
        int u = l / 5, q = l - u * 5;       // 12 x 5 chunks of 125
        const float2* wp = w2c + u * 625 + q * 125;
        const float2* gp = &Gs[wv][q * 125];
        float tre = 0.f, tim = 0.f;
        #pragma unroll 4
        for (int e = 0; e < 125; ++e) {
            float2 c = wp[e];
            float2 g = gp[e];
            tre += c.x * g.x - c.y * g.y;
            tim += c.x * g.y + c.y * g.x;
        }
        Tpar[wv][u * 5 + q] = make_float2(tre, tim);
    }
    __syncthreads();

    // ---- phase 6: layer-2 gerelu + trnorm + dense head
    if (l < 12) {
        float2 tt = make_float2(0.f, 0.f);
        #pragma unroll
        for (int q = 0; q < 5; ++q) {
            float2 A = Tpar[wv][l * 5 + q];
            tt.x += A.x; tt.y += A.y;
        }
        tr1[wv][l] = tt;
        float g = tt.x > 0.f ? tt.x : 0.f;
        gb[wv][l] = g;
        tra[wv][l] = g * sqrtf(tt.x * tt.x + tt.y * tt.y);
    }
    __syncthreads();
    if (l == 0) {
        float m = 0.f;
        #pragma unroll
        for (int u = 0; u < 12; ++u) m += tra[wv][u];
        float inv = 1.f / fmaxf(m * (1.f / 12.f), THRESH);
        float acc = db[0];
        #pragma unroll
        for (int u = 0; u < 12; ++u) {
            float s = gb[wv][u] * inv * (1.f / 3.f);
            acc += s * (tr1[wv][u].x * dw[2 * u] + tr1[wv][u].y * dw[2 * u + 1]);
        }
        out[p] = acc;
    }
}

extern "C" void kernel_launch(void* const* d_in, const int* in_sizes, int n_in,
                              void* d_out, int out_size, void* d_ws, size_t ws_size,
                              hipStream_t stream) {
    const float* x  = (const float*)d_in[0];
    const float* w1 = (const float*)d_in[1];
    const float* w2 = (const float*)d_in[2];
    const float* dw = (const float*)d_in[3];
    const float* db = (const float*)d_in[4];
    float* outp = (float*)d_out;

    geblnet_main<<<NPTS / 2, 128, 0, stream>>>(
        (const float2*)x, (const float2*)w1, (const float2*)w2, dw, db, outp);
}

// Round 12
// 168.504 us; speedup vs baseline: 1.0592x; 1.0592x over previous
//
#include <hip/hip_runtime.h>
#include <math.h>

// GEBLNet via Gram-matrix reduction (R12 = R10 pipeline x 4 waves/block).
//   T[u] = sum_{v,w} w2[u,v,w] * tr(We2[v] @ We2[w]) -> 169 unique Gram values,
//   w2 folded per-launch into CTt[169][12] float4 (setup kernel; R10/R11
//   showed the ~40us bench-vs-main gap is fixed harness overhead, so the
//   extra dispatch is free).
// Execution shape: 2048 blocks x 256 threads; each WAVE privately owns one
// point and its own LDS slice (R10-proven per-lane code, VGPR=64). 4 waves
// per workgroup slot lifts R10's ~16-workgroup/CU occupancy cap (36%) toward
// the VGPR ceiling (8 waves/SIMD). Barriers couple 4 symmetric waves only.
// Register diet (R10-proven): phase-2 w-range in two sequential halves
// (#pragma unroll 1); v-loop unroll 1 (stops global-load pipelining from
// hoarding ~50 regs — R9 evidence).
// LESSON (R11): direct w2 contraction (125 global loads/lane chain) and
// 625-entry Gram mirror both regress; keep CTt + 169-entry GV.
// LESSON (R4+R7): launch_bounds min-waves arg -> 64-VGPR quantize + spill.
// LESSON (R6): never reinterpret-cast local arrays (alloca -> scratch).

#define NPTS 8192
#define THRESH 0.001f

__global__ void geblnet_setup(const float* __restrict__ w2,
                              float4* __restrict__ CTt) {
    int j = blockIdx.x * blockDim.x + threadIdx.x;
    if (j >= 12 * 169) return;
    int u = j / 169, it = j % 169;
    const float* W = w2 + u * 25 * 25 * 2;
#define WR(v, w) W[((v) * 25 + (w)) * 2]
#define WI(v, w) W[((v) * 25 + (w)) * 2 + 1]
    float c0, c1, c2, c3;
    if (it < 78) {                       // S pairs, a<=b
        int q = it, a = 0;
        while (q >= 12 - a) { q -= 12 - a; ++a; }
        int b = a + q;
        float ar = WR(a, b) + (a != b ? WR(b, a) : 0.f);
        float ai = WI(a, b) + (a != b ? WI(b, a) : 0.f);
        float br = WR(12 + a, 12 + b) + (a != b ? WR(12 + b, 12 + a) : 0.f);
        float bi = WI(12 + a, 12 + b) + (a != b ? WI(12 + b, 12 + a) : 0.f);
        c0 = ar + br; c1 = bi - ai; c2 = ai + bi; c3 = ar - br;
    } else if (it < 156) {               // Hm pairs, a<=b
        int q = it - 78, a = 0;
        while (q >= 12 - a) { q -= 12 - a; ++a; }
        int b = a + q;
        if (a != b) {
            float gr = WR(a, 12 + b) + WR(12 + b, a);
            float gi = WI(a, 12 + b) + WI(12 + b, a);
            float dr = WR(b, 12 + a) + WR(12 + a, b);
            float di = WI(b, 12 + a) + WI(12 + a, b);
            c0 = gr + dr; c1 = di - gi; c2 = gi + di; c3 = gr - dr;
        } else {
            float er = WR(a, 12 + a) + WR(12 + a, a);
            float ei = WI(a, 12 + a) + WI(12 + a, a);
            c0 = er; c1 = 0.f; c2 = ei; c3 = 0.f;
        }
    } else if (it < 168) {               // trace terms
        int a = it - 156;
        float fr = WR(a, 24) + WR(24, a), fi = WI(a, 24) + WI(24, a);
        float pr = WR(12 + a, 24) + WR(24, 12 + a);
        float pi = WI(12 + a, 24) + WI(24, 12 + a);
        c0 = fr + pr; c1 = pi - fi; c2 = fi + pi; c3 = fr - pr;
    } else {                             // unit-unit
        c0 = 3.f * WR(24, 24); c1 = 0.f; c2 = 3.f * WI(24, 24); c3 = 0.f;
    }
    CTt[it * 12 + u] = make_float4(c0, c1, c2, c3);
#undef WR
#undef WI
}

__global__ __launch_bounds__(256) void geblnet_main(
    const float2* __restrict__ x2,      // (8192, 10, 9) complex
    const float2* __restrict__ w1g,     // (12,13,13) complex
    const float* __restrict__ dw,       // (24,)
    const float* __restrict__ db,       // (1,)
    const float4* __restrict__ CTt,     // (169,12)
    float* __restrict__ out)            // (8192,)
{
    // Per-wave private slices (4 waves = 4 points per block).
    // WeGV overlay: phases 1-2 = We1 row-major (stride 10); phases 4-5 = GV[169].
    __shared__ float2 WeGV[4][170];     // 5440 B
    // k-major: Wcol[wv][k*44 + ch*3 + j] = We[ch][j][k]; ch=12 identity at
    // 36..38; slots 39..41 ZERO (pad for h=1's 7th unroll slot).
    __shared__ float2 Wcol[4][3 * 44];  // 4224 B
    __shared__ float2 Hs[4][108];       // 3456 B
    __shared__ float2 Tpar[4][60];      // 1920 B
    __shared__ float2 tr1[4][12];       //  384 B
    __shared__ float  sc1[4][12];       //  192 B
    __shared__ float  gb[4][12];        //  192 B
    __shared__ float  tra[4][12];       //  192 B

    const int t = threadIdx.x;
    const int wv = t >> 6;              // wave id = point sub-index
    const int l = t & 63;               // lane in wave
    const int p = blockIdx.x * 4 + wv;  // 8192 = 2048*4: always valid

    float2* We = WeGV[wv];              // row-major We1, stride 10

    // ---- phase 1: build We1 in row-major (v<12) and k-major layouts
    for (int j = l; j < 117; j += 64) {
        int v = j / 9, ik = j - v * 9;
        int i = ik / 3, jj = ik - i * 3;
        if (v < 12) {
            const float2* xp = x2 + (size_t)p * 90;
            float2 val;
            if (v < 6) val = xp[(4 + v) * 9 + ik];
            else { float2 s = xp[(v - 2) * 9 + jj * 3 + i]; val = make_float2(s.x, -s.y); }
            We[v * 10 + ik] = val;                  // row-major
            Wcol[wv][jj * 44 + v * 3 + i] = val;    // k-major (k=jj)
        } else {
            Wcol[wv][jj * 44 + 36 + i] = make_float2((i == jj) ? 1.f : 0.f, 0.f);
            Wcol[wv][jj * 44 + 39 + i] = make_float2(0.f, 0.f);   // zero pad
        }
    }
    __syncthreads();

    // ---- phase 2: layer 1, lane=(u,k), sequential w-halves (R10-proven)
    if (l < 36) {
        int u = l / 3, k = l - u * 3;
        const float2* wrow = w1g + u * 169;
        float h0r = 0.f, h0i = 0.f, h1r = 0.f, h1i = 0.f, h2r = 0.f, h2i = 0.f;

        #pragma unroll 1
        for (int h = 0; h < 2; ++h) {
            const float2* wcb = &Wcol[wv][k * 44 + h * 21];   // ch = 7h + m
            float2 wc[7][3];
            #pragma unroll
            for (int m = 0; m < 7; ++m) {
                wc[m][0] = wcb[m * 3 + 0];
                wc[m][1] = wcb[m * 3 + 1];
                wc[m][2] = wcb[m * 3 + 2];
            }
            const int wlast = h ? 12 : 6;   // clamp for the padded slot

            #pragma unroll 1
            for (int v = 0; v < 13; ++v) {
                const float2* cp = wrow + v * 13 + h * 7;
                float b0r = 0.f, b0i = 0.f, b1r = 0.f, b1i = 0.f, b2r = 0.f, b2i = 0.f;
                #pragma unroll
                for (int m = 0; m < 7; ++m) {
                    float2 cc = (m == 6) ? wrow[v * 13 + wlast] : cp[m];
                    float2 e0 = wc[m][0], e1 = wc[m][1], e2 = wc[m][2];
                    b0r += cc.x * e0.x - cc.y * e0.y;  b0i += cc.x * e0.y + cc.y * e0.x;
                    b1r += cc.x * e1.x - cc.y * e1.y;  b1i += cc.x * e1.y + cc.y * e1.x;
                    b2r += cc.x * e2.x - cc.y * e2.y;  b2i += cc.x * e2.y + cc.y * e2.x;
                }
                if (v < 12) {
                    const float2* a = &We[v * 10];
                    {
                        float2 a0 = a[0], a1 = a[1], a2 = a[2];
                        h0r += a0.x * b0r - a0.y * b0i + a1.x * b1r - a1.y * b1i + a2.x * b2r - a2.y * b2i;
                        h0i += a0.x * b0i + a0.y * b0r + a1.x * b1i + a1.y * b1r + a2.x * b2i + a2.y * b2r;
                    }
                    {
                        float2 a0 = a[3], a1 = a[4], a2 = a[5];
                        h1r += a0.x * b0r - a0.y * b0i + a1.x * b1r - a1.y * b1i + a2.x * b2r - a2.y * b2i;
                        h1i += a0.x * b0i + a0.y * b0r + a1.x * b1i + a1.y * b1r + a2.x * b2i + a2.y * b2r;
                    }
                    {
                        float2 a0 = a[6], a1 = a[7], a2 = a[8];
                        h2r += a0.x * b0r - a0.y * b0i + a1.x * b1r - a1.y * b1i + a2.x * b2r - a2.y * b2i;
                        h2i += a0.x * b0i + a0.y * b0r + a1.x * b1i + a1.y * b1r + a2.x * b2i + a2.y * b2r;
                    }
                } else {                  // We[12] = I  ->  H += B(partial)
                    h0r += b0r; h0i += b0i;
                    h1r += b1r; h1i += b1i;
                    h2r += b2r; h2i += b2i;
                }
            }
        }
        Hs[wv][u * 9 + 0 + k] = make_float2(h0r, h0i);
        Hs[wv][u * 9 + 3 + k] = make_float2(h1r, h1i);
        Hs[wv][u * 9 + 6 + k] = make_float2(h2r, h2i);
    }
    __syncthreads();

    // ---- phase 3: traces + gerelu + trnorm scales
    if (l < 12) {
        float2 a = Hs[wv][l * 9 + 0], b = Hs[wv][l * 9 + 4], c = Hs[wv][l * 9 + 8];
        float2 tt = make_float2(a.x + b.x + c.x, a.y + b.y + c.y);
        tr1[wv][l] = tt;
        float gg = tt.x > 0.f ? tt.x : 0.f;
        gb[wv][l] = gg;
        tra[wv][l] = gg * sqrtf(tt.x * tt.x + tt.y * tt.y);
    }
    __syncthreads();
    if (l < 12) {
        float m = 0.f;
        #pragma unroll
        for (int u = 0; u < 12; ++u) m += tra[wv][u];
        sc1[wv][l] = gb[wv][l] / fmaxf(m * (1.f / 12.f), THRESH);
    }
    __syncthreads();

    // ---- phase 4: Gram values -> GV[169] (overlays We row-major; dead now)
    {
        float2* GV = WeGV[wv];
        for (int it = l; it < 169; it += 64) {
            float2 val;
            if (it < 156) {
                int q = it < 78 ? it : it - 78;
                float fs = sqrtf(625.0f - 8.0f * (float)q);   // exact at bucket edges
                int a = (int)((25.0f - fs) * 0.5f);
                int b = q - (a * (25 - a)) / 2 + a;
                const float2* Ha = &Hs[wv][a * 9];
                const float2* Hb = &Hs[wv][b * 9];
                float s = sc1[wv][a] * sc1[wv][b];
                float vr = 0.f, vi = 0.f;
                if (it < 78) {                    // S = tr(Aa Ab)
                    #pragma unroll
                    for (int i = 0; i < 3; ++i)
                        #pragma unroll
                        for (int jj = 0; jj < 3; ++jj) {
                            float2 A = Ha[i * 3 + jj], B = Hb[jj * 3 + i];
                            vr += A.x * B.x - A.y * B.y;
                            vi += A.x * B.y + A.y * B.x;
                        }
                } else {                          // Hm = tr(Aa Ab^H)
                    #pragma unroll
                    for (int e = 0; e < 9; ++e) {
                        float2 A = Ha[e], B = Hb[e];
                        vr += A.x * B.x + A.y * B.y;
                        vi += A.y * B.x - A.x * B.y;
                    }
                }
                val = make_float2(s * vr, s * vi);
            } else if (it < 168) {
                int a = it - 156;
                float s = sc1[wv][a]; float2 tt = tr1[wv][a];
                val = make_float2(s * tt.x, s * tt.y);
            } else {
                val = make_float2(1.f, 0.f);
            }
            GV[it] = val;
        }
    }
    __syncthreads();

    // ---- phase 5: coefficient contraction, lane=(q,u), 60 active
    if (l < 60) {
        int q = l / 12, u = l - q * 12;
        int i0 = q * 34, i1 = (q == 4) ? 169 : i0 + 34;
        float tre = 0.f, tim = 0.f;
        for (int it = i0; it < i1; ++it) {
            float4 c = CTt[it * 12 + u];
            float2 gv = WeGV[wv][it];
            tre += c.x * gv.x + c.y * gv.y;
            tim += c.z * gv.x + c.w * gv.y;
        }
        Tpar[wv][u * 5 + q] = make_float2(tre, tim);
    }
    __syncthreads();

    // ---- phase 6: layer-2 gerelu + trnorm + dense head
    if (l < 12) {
        float2 tt = make_float2(0.f, 0.f);
        #pragma unroll
        for (int q = 0; q < 5; ++q) {
            float2 A = Tpar[wv][l * 5 + q];
            tt.x += A.x; tt.y += A.y;
        }
        tr1[wv][l] = tt;
        float g = tt.x > 0.f ? tt.x : 0.f;
        gb[wv][l] = g;
        tra[wv][l] = g * sqrtf(tt.x * tt.x + tt.y * tt.y);
    }
    __syncthreads();
    if (l == 0) {
        float m = 0.f;
        #pragma unroll
        for (int u = 0; u < 12; ++u) m += tra[wv][u];
        float inv = 1.f / fmaxf(m * (1.f / 12.f), THRESH);
        float acc = db[0];
        #pragma unroll
        for (int u = 0; u < 12; ++u) {
            float s = gb[wv][u] * inv * (1.f / 3.f);
            acc += s * (tr1[wv][u].x * dw[2 * u] + tr1[wv][u].y * dw[2 * u + 1]);
        }
        out[p] = acc;
    }
}

extern "C" void kernel_launch(void* const* d_in, const int* in_sizes, int n_in,
                              void* d_out, int out_size, void* d_ws, size_t ws_size,
                              hipStream_t stream) {
    const float* x  = (const float*)d_in[0];
    const float* w1 = (const float*)d_in[1];
    const float* w2 = (const float*)d_in[2];
    const float* dw = (const float*)d_in[3];
    const float* db = (const float*)d_in[4];
    float* outp = (float*)d_out;
    float4* CTt = (float4*)d_ws;          // 12*169*16 B = 32448 B

    geblnet_setup<<<(12 * 169 + 255) / 256, 256, 0, stream>>>(w2, CTt);

    geblnet_main<<<NPTS / 4, 256, 0, stream>>>(
        (const float2*)x, (const float2*)w1, dw, db, CTt, outp);
}

// Round 13
// 165.805 us; speedup vs baseline: 1.0765x; 1.0163x over previous
//
#include <hip/hip_runtime.h>
#include <math.h>

// GEBLNet via Gram-matrix reduction (R13 = R10 + v-loop unroll 2).
//   T[u] = sum_{v,w} w2[u,v,w] * tr(We2[v] @ We2[w]) -> 169 unique Gram values,
//   w2 folded per-launch into CTt[169][12] float4 (setup kernel; the ~40us
//   bench-vs-main gap is fixed harness overhead, extra dispatch is free).
// Execution shape (R10-proven best): 8192 blocks x 64 threads, 1 wave = 1
// point, barriers are single-wave no-ops. VGPR=64 via sequential w-halves.
// R13 change: #pragma unroll 2 on the v-loop — issue v+1's 7 global w1 loads
// under v's ~120-FMA block to cover the L1 latency that left VALUBusy at 75%.
// Register cost ~+25 regs (R9's FULL unroll hoarded ~50): stays << 128 cliff.
// LESSON (R11): direct w2 contraction + 625-entry Gram mirror regress.
// LESSON (R12): multi-wave blocks regress (barrier coupling + VGPR creep);
// 1-wave workgroups are the right shape for this kernel.
// LESSON (R4+R7): launch_bounds min-waves arg -> 64-VGPR quantize + spill.
// LESSON (R6): never reinterpret-cast local arrays (alloca -> scratch).

#define NPTS 8192
#define THRESH 0.001f

__global__ void geblnet_setup(const float* __restrict__ w2,
                              float4* __restrict__ CTt) {
    int j = blockIdx.x * blockDim.x + threadIdx.x;
    if (j >= 12 * 169) return;
    int u = j / 169, it = j % 169;
    const float* W = w2 + u * 25 * 25 * 2;
#define WR(v, w) W[((v) * 25 + (w)) * 2]
#define WI(v, w) W[((v) * 25 + (w)) * 2 + 1]
    float c0, c1, c2, c3;
    if (it < 78) {                       // S pairs, a<=b
        int q = it, a = 0;
        while (q >= 12 - a) { q -= 12 - a; ++a; }
        int b = a + q;
        float ar = WR(a, b) + (a != b ? WR(b, a) : 0.f);
        float ai = WI(a, b) + (a != b ? WI(b, a) : 0.f);
        float br = WR(12 + a, 12 + b) + (a != b ? WR(12 + b, 12 + a) : 0.f);
        float bi = WI(12 + a, 12 + b) + (a != b ? WI(12 + b, 12 + a) : 0.f);
        c0 = ar + br; c1 = bi - ai; c2 = ai + bi; c3 = ar - br;
    } else if (it < 156) {               // Hm pairs, a<=b
        int q = it - 78, a = 0;
        while (q >= 12 - a) { q -= 12 - a; ++a; }
        int b = a + q;
        if (a != b) {
            float gr = WR(a, 12 + b) + WR(12 + b, a);
            float gi = WI(a, 12 + b) + WI(12 + b, a);
            float dr = WR(b, 12 + a) + WR(12 + a, b);
            float di = WI(b, 12 + a) + WI(12 + a, b);
            c0 = gr + dr; c1 = di - gi; c2 = gi + di; c3 = gr - dr;
        } else {
            float er = WR(a, 12 + a) + WR(12 + a, a);
            float ei = WI(a, 12 + a) + WI(12 + a, a);
            c0 = er; c1 = 0.f; c2 = ei; c3 = 0.f;
        }
    } else if (it < 168) {               // trace terms
        int a = it - 156;
        float fr = WR(a, 24) + WR(24, a), fi = WI(a, 24) + WI(24, a);
        float pr = WR(12 + a, 24) + WR(24, 12 + a);
        float pi = WI(12 + a, 24) + WI(24, 12 + a);
        c0 = fr + pr; c1 = pi - fi; c2 = fi + pi; c3 = fr - pr;
    } else {                             // unit-unit
        c0 = 3.f * WR(24, 24); c1 = 0.f; c2 = 3.f * WI(24, 24); c3 = 0.f;
    }
    CTt[it * 12 + u] = make_float4(c0, c1, c2, c3);
#undef WR
#undef WI
}

__global__ __launch_bounds__(64) void geblnet_main(
    const float2* __restrict__ x2,      // (8192, 10, 9) complex
    const float2* __restrict__ w1g,     // (12,13,13) complex
    const float* __restrict__ dw,       // (24,)
    const float* __restrict__ db,       // (1,)
    const float4* __restrict__ CTt,     // (169,12)
    float* __restrict__ out)            // (8192,)
{
    // Overlay: phases 1-2 = We row-major (stride 10); phases 4-5 = GV[169].
    __shared__ float2 WeGV[170];        // 1360 B
    // k-major: Wcol[k*44 + w*3 + j] = We[w][j][k]; w=12 identity at 36..38;
    // slots 39..41 ZERO (pad for h=1's 7th unroll slot).
    __shared__ float2 Wcol[3 * 44];     // 1056 B
    __shared__ float2 Hs[108];          //  864 B
    __shared__ float2 Tpar[60];         //  480 B
    __shared__ float2 tr1[12];          //   96 B
    __shared__ float  sc1[12];          //   48 B
    __shared__ float  gb[12];           //   48 B
    __shared__ float  tra[12];          //   48 B

    const int t = threadIdx.x;
    const int p = blockIdx.x;

    // ---- phase 1: build We1 in row-major (v<12) and k-major layouts
    for (int j = t; j < 117; j += 64) {
        int v = j / 9, ik = j - v * 9;
        int i = ik / 3, jj = ik - i * 3;
        if (v < 12) {
            const float2* xp = x2 + (size_t)p * 90;
            float2 val;
            if (v < 6) val = xp[(4 + v) * 9 + ik];
            else { float2 s = xp[(v - 2) * 9 + jj * 3 + i]; val = make_float2(s.x, -s.y); }
            WeGV[v * 10 + ik] = val;                // row-major
            Wcol[jj * 44 + v * 3 + i] = val;        // k-major (k=jj)
        } else {
            Wcol[jj * 44 + 36 + i] = make_float2((i == jj) ? 1.f : 0.f, 0.f);
            Wcol[jj * 44 + 39 + i] = make_float2(0.f, 0.f);   // zero pad
        }
    }
    __syncthreads();

    // ---- phase 2: layer 1, lane=(u,k), sequential w-halves
    if (t < 36) {
        int u = t / 3, k = t - u * 3;
        const float2* wrow = w1g + u * 169;
        float h0r = 0.f, h0i = 0.f, h1r = 0.f, h1i = 0.f, h2r = 0.f, h2i = 0.f;

        #pragma unroll 1
        for (int h = 0; h < 2; ++h) {
            const float2* wcb = &Wcol[k * 44 + h * 21];   // w = 7h + m
            float2 wc[7][3];
            #pragma unroll
            for (int m = 0; m < 7; ++m) {
                wc[m][0] = wcb[m * 3 + 0];
                wc[m][1] = wcb[m * 3 + 1];
                wc[m][2] = wcb[m * 3 + 2];
            }
            const int wlast = h ? 12 : 6;   // clamp for the padded slot

            #pragma unroll 2
            for (int v = 0; v < 13; ++v) {
                const float2* cp = wrow + v * 13 + h * 7;
                float b0r = 0.f, b0i = 0.f, b1r = 0.f, b1i = 0.f, b2r = 0.f, b2i = 0.f;
                #pragma unroll
                for (int m = 0; m < 7; ++m) {
                    float2 cc = (m == 6) ? wrow[v * 13 + wlast] : cp[m];
                    float2 e0 = wc[m][0], e1 = wc[m][1], e2 = wc[m][2];
                    b0r += cc.x * e0.x - cc.y * e0.y;  b0i += cc.x * e0.y + cc.y * e0.x;
                    b1r += cc.x * e1.x - cc.y * e1.y;  b1i += cc.x * e1.y + cc.y * e1.x;
                    b2r += cc.x * e2.x - cc.y * e2.y;  b2i += cc.x * e2.y + cc.y * e2.x;
                }
                if (v < 12) {
                    const float2* a = &WeGV[v * 10];
                    {
                        float2 a0 = a[0], a1 = a[1], a2 = a[2];
                        h0r += a0.x * b0r - a0.y * b0i + a1.x * b1r - a1.y * b1i + a2.x * b2r - a2.y * b2i;
                        h0i += a0.x * b0i + a0.y * b0r + a1.x * b1i + a1.y * b1r + a2.x * b2i + a2.y * b2r;
                    }
                    {
                        float2 a0 = a[3], a1 = a[4], a2 = a[5];
                        h1r += a0.x * b0r - a0.y * b0i + a1.x * b1r - a1.y * b1i + a2.x * b2r - a2.y * b2i;
                        h1i += a0.x * b0i + a0.y * b0r + a1.x * b1i + a1.y * b1r + a2.x * b2i + a2.y * b2r;
                    }
                    {
                        float2 a0 = a[6], a1 = a[7], a2 = a[8];
                        h2r += a0.x * b0r - a0.y * b0i + a1.x * b1r - a1.y * b1i + a2.x * b2r - a2.y * b2i;
                        h2i += a0.x * b0i + a0.y * b0r + a1.x * b1i + a1.y * b1r + a2.x * b2i + a2.y * b2r;
                    }
                } else {                  // We[12] = I  ->  H += B(partial)
                    h0r += b0r; h0i += b0i;
                    h1r += b1r; h1i += b1i;
                    h2r += b2r; h2i += b2i;
                }
            }
        }
        Hs[u * 9 + 0 + k] = make_float2(h0r, h0i);
        Hs[u * 9 + 3 + k] = make_float2(h1r, h1i);
        Hs[u * 9 + 6 + k] = make_float2(h2r, h2i);
    }
    __syncthreads();

    // ---- phase 3: traces + gerelu + trnorm scales
    if (t < 12) {
        float2 a = Hs[t * 9 + 0], b = Hs[t * 9 + 4], c = Hs[t * 9 + 8];
        float2 tt = make_float2(a.x + b.x + c.x, a.y + b.y + c.y);
        tr1[t] = tt;
        float gg = tt.x > 0.f ? tt.x : 0.f;
        gb[t] = gg;
        tra[t] = gg * sqrtf(tt.x * tt.x + tt.y * tt.y);
    }
    __syncthreads();
    if (t < 12) {
        float m = 0.f;
        #pragma unroll
        for (int u = 0; u < 12; ++u) m += tra[u];
        sc1[t] = gb[t] / fmaxf(m * (1.f / 12.f), THRESH);
    }
    __syncthreads();

    // ---- phase 4: Gram values -> GV (overlays We row-major; dead now)
    for (int it = t; it < 169; it += 64) {
        float2 val;
        if (it < 156) {
            int q = it < 78 ? it : it - 78;
            float fs = sqrtf(625.0f - 8.0f * (float)q);   // exact at bucket edges
            int a = (int)((25.0f - fs) * 0.5f);
            int b = q - (a * (25 - a)) / 2 + a;
            const float2* Ha = &Hs[a * 9];
            const float2* Hb = &Hs[b * 9];
            float s = sc1[a] * sc1[b];
            float vr = 0.f, vi = 0.f;
            if (it < 78) {                    // S = tr(Aa Ab)
                #pragma unroll
                for (int i = 0; i < 3; ++i)
                    #pragma unroll
                    for (int jj = 0; jj < 3; ++jj) {
                        float2 A = Ha[i * 3 + jj], B = Hb[jj * 3 + i];
                        vr += A.x * B.x - A.y * B.y;
                        vi += A.x * B.y + A.y * B.x;
                    }
            } else {                          // Hm = tr(Aa Ab^H)
                #pragma unroll
                for (int e = 0; e < 9; ++e) {
                    float2 A = Ha[e], B = Hb[e];
                    vr += A.x * B.x + A.y * B.y;
                    vi += A.y * B.x - A.x * B.y;
                }
            }
            val = make_float2(s * vr, s * vi);
        } else if (it < 168) {
            int a = it - 156;
            float s = sc1[a]; float2 tt = tr1[a];
            val = make_float2(s * tt.x, s * tt.y);
        } else {
            val = make_float2(1.f, 0.f);
        }
        WeGV[it] = val;
    }
    __syncthreads();

    // ---- phase 5: coefficient contraction, lane=(q,u), 60 active
    if (t < 60) {
        int q = t / 12, u = t - q * 12;
        int i0 = q * 34, i1 = (q == 4) ? 169 : i0 + 34;
        float tre = 0.f, tim = 0.f;
        for (int it = i0; it < i1; ++it) {
            float4 c = CTt[it * 12 + u];
            float2 gv = WeGV[it];
            tre += c.x * gv.x + c.y * gv.y;
            tim += c.z * gv.x + c.w * gv.y;
        }
        Tpar[u * 5 + q] = make_float2(tre, tim);
    }
    __syncthreads();

    // ---- phase 6: layer-2 gerelu + trnorm + dense head
    if (t < 12) {
        float2 tt = make_float2(0.f, 0.f);
        #pragma unroll
        for (int q = 0; q < 5; ++q) {
            float2 A = Tpar[t * 5 + q];
            tt.x += A.x; tt.y += A.y;
        }
        tr1[t] = tt;
        float g = tt.x > 0.f ? tt.x : 0.f;
        gb[t] = g;
        tra[t] = g * sqrtf(tt.x * tt.x + tt.y * tt.y);
    }
    __syncthreads();
    if (t == 0) {
        float m = 0.f;
        #pragma unroll
        for (int u = 0; u < 12; ++u) m += tra[u];
        float inv = 1.f / fmaxf(m * (1.f / 12.f), THRESH);
        float acc = db[0];
        #pragma unroll
        for (int u = 0; u < 12; ++u) {
            float s = gb[u] * inv * (1.f / 3.f);
            acc += s * (tr1[u].x * dw[2 * u] + tr1[u].y * dw[2 * u + 1]);
        }
        out[p] = acc;
    }
}

extern "C" void kernel_launch(void* const* d_in, const int* in_sizes, int n_in,
                              void* d_out, int out_size, void* d_ws, size_t ws_size,
                              hipStream_t stream) {
    const float* x  = (const float*)d_in[0];
    const float* w1 = (const float*)d_in[1];
    const float* w2 = (const float*)d_in[2];
    const float* dw = (const float*)d_in[3];
    const float* db = (const float*)d_in[4];
    float* outp = (float*)d_out;
    float4* CTt = (float4*)d_ws;          // 12*169*16 B = 32448 B

    geblnet_setup<<<(12 * 169 + 255) / 256, 256, 0, stream>>>(w2, CTt);

    geblnet_main<<<NPTS, 64, 0, stream>>>(
        (const float2*)x, (const float2*)w1, dw, db, CTt, outp);
}

// Round 14
// 134.662 us; speedup vs baseline: 1.3254x; 1.2313x over previous
//
#include <hip/hip_runtime.h>
#include <math.h>

// GEBLNet via Gram-matrix reduction (R14: full-64-lane layer 1 via LDS B).
//   T[u] = sum_{v,w} w2[u,v,w] * tr(We2[v] @ We2[w]) -> 169 unique Gram values,
//   w2 folded per-launch into CTt[169][12] float4 (setup kernel; ~40us
//   bench-vs-main gap is fixed harness overhead, extra dispatch is free).
// Execution shape (R10-proven): 8192 blocks x 64 threads, 1 wave = 1 point,
// barriers are intra-wave no-ops. R14 restructures layer 1 (was 36/64 lanes
// x 780 cmacs) into two LDS-staged stages on all 64 lanes:
//   2a: B[u,v,jk] = sum_w w1[u,v,w]*We[w,jk]   (702 jobs/pass, 13 cmacs each)
//   2b: H[u,ik]   = sum_{v,j} We[v,i,j]*B[u,v,j*3+k]  (54 jobs, 39 cmacs)
// run twice over u-halves reusing one 6.2KB Bs buffer. Critical-lane work
// 780 -> ~364 cmacs. We[12]=I stored -> arithmetic exact, no special case.
// LESSON (R13): VGPR>64 costs ~40% occupancy in this shape — keep demand low
// (unroll 1 on job loops; only tiny per-job state).
// LESSON (R12): multi-wave blocks regress (barrier coupling + VGPR creep).
// LESSON (R11): direct w2 contraction + 625-entry Gram mirror regress.
// LESSON (R4+R7): launch_bounds min-waves arg -> 64-VGPR quantize + spill.
// LESSON (R6): never reinterpret-cast local arrays (alloca -> scratch).

#define NPTS 8192
#define THRESH 0.001f

__global__ void geblnet_setup(const float* __restrict__ w2,
                              float4* __restrict__ CTt) {
    int j = blockIdx.x * blockDim.x + threadIdx.x;
    if (j >= 12 * 169) return;
    int u = j / 169, it = j % 169;
    const float* W = w2 + u * 25 * 25 * 2;
#define WR(v, w) W[((v) * 25 + (w)) * 2]
#define WI(v, w) W[((v) * 25 + (w)) * 2 + 1]
    float c0, c1, c2, c3;
    if (it < 78) {                       // S pairs, a<=b
        int q = it, a = 0;
        while (q >= 12 - a) { q -= 12 - a; ++a; }
        int b = a + q;
        float ar = WR(a, b) + (a != b ? WR(b, a) : 0.f);
        float ai = WI(a, b) + (a != b ? WI(b, a) : 0.f);
        float br = WR(12 + a, 12 + b) + (a != b ? WR(12 + b, 12 + a) : 0.f);
        float bi = WI(12 + a, 12 + b) + (a != b ? WI(12 + b, 12 + a) : 0.f);
        c0 = ar + br; c1 = bi - ai; c2 = ai + bi; c3 = ar - br;
    } else if (it < 156) {               // Hm pairs, a<=b
        int q = it - 78, a = 0;
        while (q >= 12 - a) { q -= 12 - a; ++a; }
        int b = a + q;
        if (a != b) {
            float gr = WR(a, 12 + b) + WR(12 + b, a);
            float gi = WI(a, 12 + b) + WI(12 + b, a);
            float dr = WR(b, 12 + a) + WR(12 + a, b);
            float di = WI(b, 12 + a) + WI(12 + a, b);
            c0 = gr + dr; c1 = di - gi; c2 = gi + di; c3 = gr - dr;
        } else {
            float er = WR(a, 12 + a) + WR(12 + a, a);
            float ei = WI(a, 12 + a) + WI(12 + a, a);
            c0 = er; c1 = 0.f; c2 = ei; c3 = 0.f;
        }
    } else if (it < 168) {               // trace terms
        int a = it - 156;
        float fr = WR(a, 24) + WR(24, a), fi = WI(a, 24) + WI(24, a);
        float pr = WR(12 + a, 24) + WR(24, 12 + a);
        float pi = WI(12 + a, 24) + WI(24, 12 + a);
        c0 = fr + pr; c1 = pi - fi; c2 = fi + pi; c3 = fr - pr;
    } else {                             // unit-unit
        c0 = 3.f * WR(24, 24); c1 = 0.f; c2 = 3.f * WI(24, 24); c3 = 0.f;
    }
    CTt[it * 12 + u] = make_float4(c0, c1, c2, c3);
#undef WR
#undef WI
}

__global__ __launch_bounds__(64) void geblnet_main(
    const float2* __restrict__ x2,      // (8192, 10, 9) complex
    const float2* __restrict__ w1g,     // (12,13,13) complex
    const float* __restrict__ dw,       // (24,)
    const float* __restrict__ db,       // (1,)
    const float4* __restrict__ CTt,     // (169,12)
    float* __restrict__ out)            // (8192,)
{
    // Overlay: phases 1-2 = We row-major (13 ch incl. identity, stride 10);
    //          phases 4-5 = GV[169].
    __shared__ float2 WeGV[170];        // 1360 B
    __shared__ float2 Bs[780];          // 6240 B: B[uu][v][jk], rows pad 10
    __shared__ float2 Hs[108];          //  864 B
    __shared__ float2 Tpar[60];         //  480 B
    __shared__ float2 tr1[12];          //   96 B
    __shared__ float  sc1[12];          //   48 B
    __shared__ float  gb[12];           //   48 B
    __shared__ float  tra[12];          //   48 B

    const int t = threadIdx.x;
    const int p = blockIdx.x;

    // ---- phase 1: build We channels 0..12 (12 data + identity), stride 10
    for (int j = t; j < 117; j += 64) {
        int v = j / 9, ik = j - v * 9;
        int i = ik / 3, jj = ik - i * 3;
        float2 val;
        if (v < 6) val = x2[(size_t)p * 90 + (4 + v) * 9 + ik];
        else if (v < 12) {
            float2 s = x2[(size_t)p * 90 + (v - 2) * 9 + jj * 3 + i];
            val = make_float2(s.x, -s.y);
        } else val = make_float2((i == jj) ? 1.f : 0.f, 0.f);
        WeGV[v * 10 + ik] = val;
    }
    __syncthreads();

    // ---- phase 2: layer 1 on all 64 lanes, two u-half passes
    #pragma unroll 1
    for (int g = 0; g < 2; ++g) {
        const int u0 = g * 6;
        // 2a: B[uu][v][jk] = sum_w w1[u0+uu,v,w] * We[w][jk]
        #pragma unroll 1
        for (int e = t; e < 702; e += 64) {
            int uu = e / 117, rem = e - uu * 117;
            int v = rem / 9, jk = rem - v * 9;
            const float2* cp = w1g + ((u0 + uu) * 13 + v) * 13;
            float br = 0.f, bi = 0.f;
            #pragma unroll
            for (int w = 0; w < 13; ++w) {
                float2 cc = cp[w];
                float2 ee = WeGV[w * 10 + jk];
                br += cc.x * ee.x - cc.y * ee.y;
                bi += cc.x * ee.y + cc.y * ee.x;
            }
            Bs[(uu * 13 + v) * 10 + jk] = make_float2(br, bi);
        }
        __syncthreads();
        // 2b: H[u0+uu][i][k] = sum_{v,j} We[v][i][j] * B[uu][v][j*3+k]
        if (t < 54) {
            int uu = t / 9, ik = t - uu * 9;
            int i = ik / 3, k = ik - i * 3;
            float hr = 0.f, hi = 0.f;
            #pragma unroll
            for (int v = 0; v < 13; ++v) {
                const float2* a = &WeGV[v * 10 + i * 3];
                const float2* b = &Bs[(uu * 13 + v) * 10 + k];
                #pragma unroll
                for (int j = 0; j < 3; ++j) {
                    float2 aj = a[j];
                    float2 bj = b[j * 3];
                    hr += aj.x * bj.x - aj.y * bj.y;
                    hi += aj.x * bj.y + aj.y * bj.x;
                }
            }
            Hs[(u0 + uu) * 9 + ik] = make_float2(hr, hi);
        }
        __syncthreads();
    }

    // ---- phase 3: traces + gerelu + trnorm scales
    if (t < 12) {
        float2 a = Hs[t * 9 + 0], b = Hs[t * 9 + 4], c = Hs[t * 9 + 8];
        float2 tt = make_float2(a.x + b.x + c.x, a.y + b.y + c.y);
        tr1[t] = tt;
        float gg = tt.x > 0.f ? tt.x : 0.f;
        gb[t] = gg;
        tra[t] = gg * sqrtf(tt.x * tt.x + tt.y * tt.y);
    }
    __syncthreads();
    if (t < 12) {
        float m = 0.f;
        #pragma unroll
        for (int u = 0; u < 12; ++u) m += tra[u];
        sc1[t] = gb[t] / fmaxf(m * (1.f / 12.f), THRESH);
    }
    __syncthreads();

    // ---- phase 4: Gram values -> GV (overlays We row-major; dead now)
    for (int it = t; it < 169; it += 64) {
        float2 val;
        if (it < 156) {
            int q = it < 78 ? it : it - 78;
            float fs = sqrtf(625.0f - 8.0f * (float)q);   // exact at bucket edges
            int a = (int)((25.0f - fs) * 0.5f);
            int b = q - (a * (25 - a)) / 2 + a;
            const float2* Ha = &Hs[a * 9];
            const float2* Hb = &Hs[b * 9];
            float s = sc1[a] * sc1[b];
            float vr = 0.f, vi = 0.f;
            if (it < 78) {                    // S = tr(Aa Ab)
                #pragma unroll
                for (int i = 0; i < 3; ++i)
                    #pragma unroll
                    for (int jj = 0; jj < 3; ++jj) {
                        float2 A = Ha[i * 3 + jj], B = Hb[jj * 3 + i];
                        vr += A.x * B.x - A.y * B.y;
                        vi += A.x * B.y + A.y * B.x;
                    }
            } else {                          // Hm = tr(Aa Ab^H)
                #pragma unroll
                for (int e = 0; e < 9; ++e) {
                    float2 A = Ha[e], B = Hb[e];
                    vr += A.x * B.x + A.y * B.y;
                    vi += A.y * B.x - A.x * B.y;
                }
            }
            val = make_float2(s * vr, s * vi);
        } else if (it < 168) {
            int a = it - 156;
            float s = sc1[a]; float2 tt = tr1[a];
            val = make_float2(s * tt.x, s * tt.y);
        } else {
            val = make_float2(1.f, 0.f);
        }
        WeGV[it] = val;
    }
    __syncthreads();

    // ---- phase 5: coefficient contraction, lane=(q,u), 60 active
    if (t < 60) {
        int q = t / 12, u = t - q * 12;
        int i0 = q * 34, i1 = (q == 4) ? 169 : i0 + 34;
        float tre = 0.f, tim = 0.f;
        for (int it = i0; it < i1; ++it) {
            float4 c = CTt[it * 12 + u];
            float2 gv = WeGV[it];
            tre += c.x * gv.x + c.y * gv.y;
            tim += c.z * gv.x + c.w * gv.y;
        }
        Tpar[u * 5 + q] = make_float2(tre, tim);
    }
    __syncthreads();

    // ---- phase 6: layer-2 gerelu + trnorm + dense head
    if (t < 12) {
        float2 tt = make_float2(0.f, 0.f);
        #pragma unroll
        for (int q = 0; q < 5; ++q) {
            float2 A = Tpar[t * 5 + q];
            tt.x += A.x; tt.y += A.y;
        }
        tr1[t] = tt;
        float g = tt.x > 0.f ? tt.x : 0.f;
        gb[t] = g;
        tra[t] = g * sqrtf(tt.x * tt.x + tt.y * tt.y);
    }
    __syncthreads();
    if (t == 0) {
        float m = 0.f;
        #pragma unroll
        for (int u = 0; u < 12; ++u) m += tra[u];
        float inv = 1.f / fmaxf(m * (1.f / 12.f), THRESH);
        float acc = db[0];
        #pragma unroll
        for (int u = 0; u < 12; ++u) {
            float s = gb[u] * inv * (1.f / 3.f);
            acc += s * (tr1[u].x * dw[2 * u] + tr1[u].y * dw[2 * u + 1]);
        }
        out[p] = acc;
    }
}

extern "C" void kernel_launch(void* const* d_in, const int* in_sizes, int n_in,
                              void* d_out, int out_size, void* d_ws, size_t ws_size,
                              hipStream_t stream) {
    const float* x  = (const float*)d_in[0];
    const float* w1 = (const float*)d_in[1];
    const float* w2 = (const float*)d_in[2];
    const float* dw = (const float*)d_in[3];
    const float* db = (const float*)d_in[4];
    float* outp = (float*)d_out;
    float4* CTt = (float4*)d_ws;          // 12*169*16 B = 32448 B

    geblnet_setup<<<(12 * 169 + 255) / 256, 256, 0, stream>>>(w2, CTt);

    geblnet_main<<<NPTS, 64, 0, stream>>>(
        (const float2*)x, (const float2*)w1, dw, db, CTt, outp);
}